// Round 8
// baseline (342.707 us; speedup 1.0000x reference)
//
#include <hip/hip_runtime.h>
#include <hip/hip_bf16.h>
#include <math.h>

typedef __bf16 bf16;
typedef __bf16 bf16x4 __attribute__((ext_vector_type(4)));
typedef __bf16 bf16x8 __attribute__((ext_vector_type(8)));
typedef float f32x4 __attribute__((ext_vector_type(4)));

#define OCC 230
#define NRELS 53
// ws bf16-elem offsets (all 16B aligned)
#define W2V48_OFF 0        // 50000 x 48 (dims 0..47)
#define WTAIL_OFF 2400000  // 50000 x 2  (d48,d49) dword-packed
#define PCAT_OFF  2500000  // 3721 x 16: [p1_0..4, p2_0, 0, 0 | p2_1..4, 0,0,0,0]
#define REMBB_OFF 2559552  // 64 x 768 (col = p*256+oc)
#define CONVB_OFF 2608704  // 256 x 192, K' = tap*64+d (d>=60 or oc>=230 -> 0)
#define FLWS_OFF  2657864  // 8000 x 768 bf16 tanh features

union FragU { bf16x8 v8; bf16x4 v4[2]; bf16 e[8]; };

// ---- prep: build bf16 tables ----
__global__ void pcnn_prep(const float* __restrict__ w2v, const float* __restrict__ p1e,
                          const float* __restrict__ p2e, const float* __restrict__ remb,
                          const float* __restrict__ convw, bf16* __restrict__ wsb) {
  const int i = blockIdx.x * 256 + threadIdx.x;
  if (i < 300000) {                       // w2v48
    const int w = i / 6, c = i - 6 * w;
    const float2* s = reinterpret_cast<const float2*>(w2v + w * 50 + c * 8);
    const float2 f0 = s[0], f1 = s[1], f2 = s[2], f3 = s[3];
    bf16x8 v = {(bf16)f0.x, (bf16)f0.y, (bf16)f1.x, (bf16)f1.y,
                (bf16)f2.x, (bf16)f2.y, (bf16)f3.x, (bf16)f3.y};
    *reinterpret_cast<bf16x8*>(wsb + W2V48_OFF + w * 48 + c * 8) = v;
    return;
  }
  int e = i - 300000;
  if (e < 50000) {                        // wtail
    const float2 f = *reinterpret_cast<const float2*>(w2v + e * 50 + 48);
    wsb[WTAIL_OFF + 2 * e]     = (bf16)f.x;
    wsb[WTAIL_OFF + 2 * e + 1] = (bf16)f.y;
    return;
  }
  e -= 50000;
  if (e < 7442) {                         // pcat16 halves
    const int row = e >> 1, h = e & 1;
    const int v1 = row / 61, v2 = row - v1 * 61;
    bf16x8 v;
    if (h == 0) {
      v[0] = (bf16)p1e[v1 * 5 + 0]; v[1] = (bf16)p1e[v1 * 5 + 1];
      v[2] = (bf16)p1e[v1 * 5 + 2]; v[3] = (bf16)p1e[v1 * 5 + 3];
      v[4] = (bf16)p1e[v1 * 5 + 4]; v[5] = (bf16)p2e[v2 * 5 + 0];
      v[6] = (bf16)0.f; v[7] = (bf16)0.f;
    } else {
      v[0] = (bf16)p2e[v2 * 5 + 1]; v[1] = (bf16)p2e[v2 * 5 + 2];
      v[2] = (bf16)p2e[v2 * 5 + 3]; v[3] = (bf16)p2e[v2 * 5 + 4];
      v[4] = (bf16)0.f; v[5] = (bf16)0.f; v[6] = (bf16)0.f; v[7] = (bf16)0.f;
    }
    *reinterpret_cast<bf16x8*>(wsb + PCAT_OFF + row * 16 + h * 8) = v;
    return;
  }
  e -= 7442;
  if (e < 6144) {                         // rembb [64][768]
    const int r = e / 96, c0 = (e - r * 96) * 8;
    bf16x8 v;
#pragma unroll
    for (int j = 0; j < 8; ++j) {
      const int cc = c0 + j, p = cc >> 8, oc = cc & 255;
      v[j] = (r < NRELS && oc < OCC) ? (bf16)remb[r * 690 + p * OCC + oc] : (bf16)0.f;
    }
    *reinterpret_cast<bf16x8*>(wsb + REMBB_OFF + r * 768 + c0) = v;
    return;
  }
  e -= 6144;
  if (e < 6144) {                         // convb64 [256][192], K' = tap*64+d
    const int oc = e / 24, k0 = (e - oc * 24) * 8;
    bf16x8 v;
#pragma unroll
    for (int j = 0; j < 8; ++j) {
      const int kp = k0 + j, tap = kp >> 6, d = kp & 63;
      v[j] = (oc < OCC && d < 60) ? (bf16)convw[oc * 180 + tap * 60 + d] : (bf16)0.f;
    }
    *reinterpret_cast<bf16x8*>(wsb + CONVB_OFF + oc * 192 + k0) = v;
  }
}

// ---- K1: conv+pool+tanh; block = 4 sentences, 8 waves, dbuf async gather ----
#define XROWS 122
#define XSTR 64
#define XBUFE (XROWS * XSTR)   // 7808 elems; LDS row r = x row r-1; rows 0,121 zero

__global__ __launch_bounds__(512, 4)
void pcnn_conv(const int* __restrict__ words, const int* __restrict__ posi,
               const float* __restrict__ cb0, const float* __restrict__ cb1,
               const float* __restrict__ cb2, const bf16* __restrict__ wsb,
               bf16* __restrict__ flws)
{
  __shared__ __align__(16) bf16 xb[2][XBUFE];   // 31.2 KB
  __shared__ int widx[480];                     // word | pidx<<16 | piece<<28

  const int t = threadIdx.x;
  const int sb = blockIdx.x * 4;     // first sentence of this block
  const int wv = t >> 6, lane = t & 63, g = lane >> 4, cl = lane & 15;

  // ids for 4 sentences
  if (t < 480) {
    const int w = words[sb * 120 + t];
    const int2 pp = *reinterpret_cast<const int2*>(posi + sb * 240 + 2 * t);
    const bool b0 = pp.x >= 30, b1 = pp.y >= 30;
    const int pc = (b0 && b1) ? 0 : ((!b0 && !b1) ? 2 : 1);
    widx[t] = w | ((pp.x * 61 + pp.y) << 16) | (pc << 28);
  }
  // zero both x buffers (rows 0/121 + masked slots rely on this)
  {
    int4* z = reinterpret_cast<int4*>(&xb[0][0]);
#pragma unroll
    for (int i = 0; i < 4; ++i) {
      const int idx = t + i * 512;
      if (idx < 2 * XBUFE / 8) z[idx] = int4{0, 0, 0, 0};
    }
  }

  // conv weights (K'-layout) -> regs
  FragU Bf[2][6];
  {
    const bf16* cwb = wsb + CONVB_OFF;
#pragma unroll
    for (int nt = 0; nt < 2; ++nt) {
      const int oc = wv * 32 + nt * 16 + cl;
#pragma unroll
      for (int ks = 0; ks < 6; ++ks)
        Bf[nt][ks].v8 = *reinterpret_cast<const bf16x8*>(cwb + oc * 192 + ks * 32 + g * 8);
    }
  }
  // pool biases hoisted
  float bias[2][3];
#pragma unroll
  for (int nt = 0; nt < 2; ++nt) {
    const int ocg = wv * 32 + nt * 16 + cl;
    const int occ = (ocg < OCC) ? ocg : 0;
    bias[nt][0] = cb0[occ]; bias[nt][1] = cb1[occ]; bias[nt][2] = cb2[occ];
  }

  __syncthreads();  // widx + zeros ready

  // async W gather: chunks 0..5 of rows 1..120, source-permuted for XOR swizzle
  auto issue_gather = [&](int s, int nb) {
    const int* wr = &widx[s * 120];
#pragma unroll
    for (int i = 0; i < 2; ++i) {
      const int slotb = wv * 128 + i * 64;
      const int slot = slotb + lane;
      const int row = slot >> 3;
      const int c16 = (slot & 7) ^ (row & 7);
      bf16* dst = &xb[nb][slotb * 8];            // wave-uniform; HW adds lane*16B
      if (row >= 1 && row <= 120 && c16 < 6) {
        const int word = wr[row - 1] & 0xFFFF;
        const bf16* src = wsb + W2V48_OFF + word * 48 + c16 * 8;
        __builtin_amdgcn_global_load_lds(
            (const __attribute__((address_space(1))) void*)src,
            (__attribute__((address_space(3))) void*)dst, 16, 0, 0);
      }
    }
  };
  // reg-staged tail: chunks 6,7 (d48..59 + zeros), swizzled ds_write
  auto stage_tail = [&](int s, int nb) {
    if (t < 120) {
      const int wi = widx[s * 120 + t];
      const int word = wi & 0xFFFF;
      const int pidx = (wi >> 16) & 0xFFF;
      const int row = t + 1;
      const int wt = *(reinterpret_cast<const int*>(wsb + WTAIL_OFF) + word);
      const int4 pcA = *reinterpret_cast<const int4*>(wsb + PCAT_OFF + pidx * 16);
      const int4 pcB = *reinterpret_cast<const int4*>(wsb + PCAT_OFF + pidx * 16 + 8);
      const int sw6 = 6 ^ (row & 7), sw7 = 7 ^ (row & 7);
      *reinterpret_cast<int4*>(&xb[nb][row * XSTR + sw6 * 8]) = int4{wt, pcA.x, pcA.y, pcA.z};
      *reinterpret_cast<int4*>(&xb[nb][row * XSTR + sw7 * 8]) = pcB;
    }
  };

  issue_gather(0, 0);
  stage_tail(0, 0);
  asm volatile("s_waitcnt vmcnt(0)" ::: "memory");
  __syncthreads();

  int mrowT[8];
#pragma unroll
  for (int mt = 0; mt < 8; ++mt) {
    const int m = mt * 16 + cl;
    mrowT[mt] = (m < 120 ? m : 119) * XSTR;
  }

  for (int s = 0; s < 4; ++s) {
    const int nb = s & 1;
    if (s < 3) { issue_gather(s + 1, nb ^ 1); stage_tail(s + 1, nb ^ 1); }

    // conv GEMM: 96 MFMA/wave (8 mt x 2 nt x 6 ks), swizzled b128 A-reads
    f32x4 acc[8][2];
    const f32x4 z4 = {0.f, 0.f, 0.f, 0.f};
#pragma unroll
    for (int mt = 0; mt < 8; ++mt) { acc[mt][0] = z4; acc[mt][1] = z4; }

#pragma unroll
    for (int ks = 0; ks < 6; ++ks) {
      const int kp = ks * 32 + g * 8;
      const int tap = kp >> 6;
      const int d8 = (kp >> 3) & 7;
      const int sw = tap * XSTR + ((d8 ^ ((cl + tap) & 7)) << 3);
#pragma unroll
      for (int mt = 0; mt < 8; ++mt) {
        FragU a;
        a.v8 = *reinterpret_cast<const bf16x8*>(&xb[nb][mrowT[mt] + sw]);
#pragma unroll
        for (int nt = 0; nt < 2; ++nt)
          acc[mt][nt] = __builtin_amdgcn_mfma_f32_16x16x32_bf16(
              a.v8, Bf[nt][ks].v8, acc[mt][nt], 0, 0, 0);
      }
    }

    // piecewise masked max-pool (masked-out contributes 0)
    float pool[2][3];
#pragma unroll
    for (int nt = 0; nt < 2; ++nt) { pool[nt][0] = pool[nt][1] = pool[nt][2] = -INFINITY; }
#pragma unroll
    for (int mt = 0; mt < 8; ++mt) {
      const int l0 = mt * 16 + g * 4;
      if (l0 < 120) {
        const int4 pv = *reinterpret_cast<const int4*>(&widx[s * 120 + l0]);
        const int pcs[4] = {(int)((unsigned)pv.x >> 28), (int)((unsigned)pv.y >> 28),
                            (int)((unsigned)pv.z >> 28), (int)((unsigned)pv.w >> 28)};
#pragma unroll
        for (int r = 0; r < 4; ++r) {
          const int p = pcs[r];
#pragma unroll
          for (int nt = 0; nt < 2; ++nt) {
            const float v = acc[mt][nt][r];
            pool[nt][0] = fmaxf(pool[nt][0], p == 0 ? v : 0.0f);
            pool[nt][1] = fmaxf(pool[nt][1], p == 1 ? v : 0.0f);
            pool[nt][2] = fmaxf(pool[nt][2], p == 2 ? v : 0.0f);
          }
        }
      }
    }
#pragma unroll
    for (int nt = 0; nt < 2; ++nt)
#pragma unroll
      for (int p = 0; p < 3; ++p) {
        float x = pool[nt][p];
        x = fmaxf(x, __shfl_xor(x, 16));
        x = fmaxf(x, __shfl_xor(x, 32));
        pool[nt][p] = x;
      }
    if (g == 0) {
#pragma unroll
      for (int nt = 0; nt < 2; ++nt) {
        const int ocg = wv * 32 + nt * 16 + cl;
        if (ocg < OCC) {
          bf16* fr = flws + (sb + s) * 768;
          fr[ocg]       = (bf16)tanhf(pool[nt][0] + bias[nt][0]);
          fr[256 + ocg] = (bf16)tanhf(pool[nt][1] + bias[nt][1]);
          fr[512 + ocg] = (bf16)tanhf(pool[nt][2] + bias[nt][2]);
        }
      }
    }

    asm volatile("s_waitcnt vmcnt(0)" ::: "memory");  // gather(s+1) landed
    __syncthreads();                                   // buffer handoff
  }
}

// ---- K2: batched logits GEMM + softmax + bag-max, one bag per block ----
__global__ __launch_bounds__(256)
void pcnn_logits(const bf16* __restrict__ wsb, const bf16* __restrict__ flws,
                 const float* __restrict__ rbias, float* __restrict__ out)
{
  __shared__ __align__(16) bf16 fl_lds[6144];  // [8 sent][768]
  __shared__ float logits_l[8][64];

  const int t = threadIdx.x;
  const int bag = blockIdx.x;
  const int wv = t >> 6, lane = t & 63, g = lane >> 4, cl = lane & 15;

#pragma unroll
  for (int j = 0; j < 3; ++j) {
    const bf16* src = flws + bag * 6144 + (j * 256 + t) * 8;
    bf16* dst = &fl_lds[(j * 256 + wv * 64) * 8];
    __builtin_amdgcn_global_load_lds(
        (const __attribute__((address_space(1))) void*)src,
        (__attribute__((address_space(3))) void*)dst, 16, 0, 0);
  }
  asm volatile("s_waitcnt vmcnt(0)" ::: "memory");
  __syncthreads();

  f32x4 lac = {0.f, 0.f, 0.f, 0.f};
  const bf16* brow = wsb + REMBB_OFF + (wv * 16 + cl) * 768 + g * 8;
  const bf16x8 zf = {(bf16)0.f, (bf16)0.f, (bf16)0.f, (bf16)0.f,
                     (bf16)0.f, (bf16)0.f, (bf16)0.f, (bf16)0.f};
#pragma unroll
  for (int ks = 0; ks < 24; ++ks) {
    const bf16x8 afr = (cl < 8)
        ? *reinterpret_cast<const bf16x8*>(&fl_lds[cl * 768 + ks * 32 + g * 8]) : zf;
    const bf16x8 bfr = *reinterpret_cast<const bf16x8*>(brow + ks * 32);
    lac = __builtin_amdgcn_mfma_f32_16x16x32_bf16(afr, bfr, lac, 0, 0, 0);
  }
  if (g < 2) {
    const int rel = wv * 16 + cl;
    const float bias = (rel < NRELS) ? rbias[rel] : 0.0f;
#pragma unroll
    for (int r = 0; r < 4; ++r)
      logits_l[g * 4 + r][rel] = lac[r] * 0.5f + bias;
  }
  __syncthreads();

#pragma unroll
  for (int rep = 0; rep < 2; ++rep) {
    const int s = wv + rep * 4;
    const float x = (lane < NRELS) ? logits_l[s][lane] : -INFINITY;
    float m = x;
#pragma unroll
    for (int off = 32; off; off >>= 1) m = fmaxf(m, __shfl_xor(m, off));
    const float e = (lane < NRELS) ? __expf(x - m) : 0.0f;
    float sm = e;
#pragma unroll
    for (int off = 32; off; off >>= 1) sm += __shfl_xor(sm, off);
    if (lane < NRELS) logits_l[s][lane] = x - m - __logf(sm);
  }
  __syncthreads();

  if (t < NRELS) {
    float m = logits_l[0][t];
#pragma unroll
    for (int s2 = 1; s2 < 8; ++s2) m = fmaxf(m, logits_l[s2][t]);
    out[bag * NRELS + t] = m;
  }
}

extern "C" void kernel_launch(void* const* d_in, const int* in_sizes, int n_in,
                              void* d_out, int out_size, void* d_ws, size_t ws_size,
                              hipStream_t stream) {
  const int* words  = (const int*)d_in[0];
  const int* posi   = (const int*)d_in[1];
  const float* w2v  = (const float*)d_in[2];
  const float* p1e  = (const float*)d_in[3];
  const float* p2e  = (const float*)d_in[4];
  const float* cw   = (const float*)d_in[5];
  const float* cb0  = (const float*)d_in[6];
  const float* cb1  = (const float*)d_in[7];
  const float* cb2  = (const float*)d_in[8];
  const float* remb = (const float*)d_in[9];
  const float* rbias= (const float*)d_in[10];
  bf16* wsb = (bf16*)d_ws;
  bf16* flws = wsb + FLWS_OFF;
  float* out = (float*)d_out;

  pcnn_prep<<<1445, 256, 0, stream>>>(w2v, p1e, p2e, remb, cw, wsb);
  pcnn_conv<<<2000, 512, 0, stream>>>(words, posi, cb0, cb1, cb2, wsb, flws);
  pcnn_logits<<<1000, 256, 0, stream>>>(wsb, flws, rbias, out);
}

// Round 9
// 314.505 us; speedup vs baseline: 1.0897x; 1.0897x over previous
//
#include <hip/hip_runtime.h>
#include <hip/hip_bf16.h>
#include <math.h>

typedef __bf16 bf16;
typedef __bf16 bf16x4 __attribute__((ext_vector_type(4)));
typedef __bf16 bf16x8 __attribute__((ext_vector_type(8)));
typedef float f32x4 __attribute__((ext_vector_type(4)));

#define OCC 230
#define NRELS 53
// ws bf16-elem offsets (all 16B aligned)
#define W2V48_OFF 0        // 50000 x 48 (dims 0..47)
#define WTAIL_OFF 2400000  // 50000 x 2  (d48,d49) dword-packed
#define PCAT_OFF  2500000  // 3721 x 16: [p1_0..4, p2_0, 0, 0 | p2_1..4, 0,0,0,0]
#define REMBB_OFF 2559552  // 64 x 768 (col = p*256+oc)
#define CONVB_OFF 2608704  // 256 x 192, K' = tap*64+d (d>=60 or oc>=230 -> 0)
#define FLWS_OFF  2657864  // 8000 x 768 bf16 tanh features

union FragU { bf16x8 v8; bf16x4 v4[2]; bf16 e[8]; };

// ---- prep: build bf16 tables ----
__global__ void pcnn_prep(const float* __restrict__ w2v, const float* __restrict__ p1e,
                          const float* __restrict__ p2e, const float* __restrict__ remb,
                          const float* __restrict__ convw, bf16* __restrict__ wsb) {
  const int i = blockIdx.x * 256 + threadIdx.x;
  if (i < 300000) {                       // w2v48
    const int w = i / 6, c = i - 6 * w;
    const float2* s = reinterpret_cast<const float2*>(w2v + w * 50 + c * 8);
    const float2 f0 = s[0], f1 = s[1], f2 = s[2], f3 = s[3];
    bf16x8 v = {(bf16)f0.x, (bf16)f0.y, (bf16)f1.x, (bf16)f1.y,
                (bf16)f2.x, (bf16)f2.y, (bf16)f3.x, (bf16)f3.y};
    *reinterpret_cast<bf16x8*>(wsb + W2V48_OFF + w * 48 + c * 8) = v;
    return;
  }
  int e = i - 300000;
  if (e < 50000) {                        // wtail
    const float2 f = *reinterpret_cast<const float2*>(w2v + e * 50 + 48);
    wsb[WTAIL_OFF + 2 * e]     = (bf16)f.x;
    wsb[WTAIL_OFF + 2 * e + 1] = (bf16)f.y;
    return;
  }
  e -= 50000;
  if (e < 7442) {                         // pcat16 halves
    const int row = e >> 1, h = e & 1;
    const int v1 = row / 61, v2 = row - v1 * 61;
    bf16x8 v;
    if (h == 0) {
      v[0] = (bf16)p1e[v1 * 5 + 0]; v[1] = (bf16)p1e[v1 * 5 + 1];
      v[2] = (bf16)p1e[v1 * 5 + 2]; v[3] = (bf16)p1e[v1 * 5 + 3];
      v[4] = (bf16)p1e[v1 * 5 + 4]; v[5] = (bf16)p2e[v2 * 5 + 0];
      v[6] = (bf16)0.f; v[7] = (bf16)0.f;
    } else {
      v[0] = (bf16)p2e[v2 * 5 + 1]; v[1] = (bf16)p2e[v2 * 5 + 2];
      v[2] = (bf16)p2e[v2 * 5 + 3]; v[3] = (bf16)p2e[v2 * 5 + 4];
      v[4] = (bf16)0.f; v[5] = (bf16)0.f; v[6] = (bf16)0.f; v[7] = (bf16)0.f;
    }
    *reinterpret_cast<bf16x8*>(wsb + PCAT_OFF + row * 16 + h * 8) = v;
    return;
  }
  e -= 7442;
  if (e < 6144) {                         // rembb [64][768]
    const int r = e / 96, c0 = (e - r * 96) * 8;
    bf16x8 v;
#pragma unroll
    for (int j = 0; j < 8; ++j) {
      const int cc = c0 + j, p = cc >> 8, oc = cc & 255;
      v[j] = (r < NRELS && oc < OCC) ? (bf16)remb[r * 690 + p * OCC + oc] : (bf16)0.f;
    }
    *reinterpret_cast<bf16x8*>(wsb + REMBB_OFF + r * 768 + c0) = v;
    return;
  }
  e -= 6144;
  if (e < 6144) {                         // convb64 [256][192], K' = tap*64+d
    const int oc = e / 24, k0 = (e - oc * 24) * 8;
    bf16x8 v;
#pragma unroll
    for (int j = 0; j < 8; ++j) {
      const int kp = k0 + j, tap = kp >> 6, d = kp & 63;
      v[j] = (oc < OCC && d < 60) ? (bf16)convw[oc * 180 + tap * 60 + d] : (bf16)0.f;
    }
    *reinterpret_cast<bf16x8*>(wsb + CONVB_OFF + oc * 192 + k0) = v;
  }
}

// ---- K1: conv+pool+tanh; block = (oc-half, 4 sentences), 4 waves, dbuf gather ----
#define XROWS 122
#define XSTR 64
#define XBUFE (XROWS * XSTR)   // 7808 elems; LDS row r = x row r-1; rows 0,121 zero

__global__ __launch_bounds__(256, 3)
void pcnn_conv(const int* __restrict__ words, const int* __restrict__ posi,
               const float* __restrict__ cb0, const float* __restrict__ cb1,
               const float* __restrict__ cb2, const bf16* __restrict__ wsb,
               bf16* __restrict__ flws)
{
  __shared__ __align__(16) bf16 xb[2][XBUFE];   // 31.2 KB
  __shared__ int widx[480];                     // word | pidx<<16 | piece<<28

  const int t = threadIdx.x;
  const int grp = blockIdx.x >> 1;
  const int ochalf = blockIdx.x & 1;
  const int sb = grp * 4;            // first sentence of this block
  const int wv = t >> 6, lane = t & 63, g = lane >> 4, cl = lane & 15;

  // ids for 4 sentences
#pragma unroll
  for (int i = 0; i < 2; ++i) {
    const int idx = t + i * 256;
    if (idx < 480) {
      const int w = words[sb * 120 + idx];
      const int2 pp = *reinterpret_cast<const int2*>(posi + sb * 240 + 2 * idx);
      const bool b0 = pp.x >= 30, b1 = pp.y >= 30;
      const int pc = (b0 && b1) ? 0 : ((!b0 && !b1) ? 2 : 1);
      widx[idx] = w | ((pp.x * 61 + pp.y) << 16) | (pc << 28);
    }
  }
  // zero both x buffers (rows 0/121 rely on this persisting)
  {
    int4* z = reinterpret_cast<int4*>(&xb[0][0]);
    for (int i = t; i < 2 * XBUFE / 8; i += 256) z[i] = int4{0, 0, 0, 0};
  }

  // conv weights (K'-layout) -> regs: this block's 128-oc half
  FragU Bf[2][6];
  {
    const bf16* cwb = wsb + CONVB_OFF;
#pragma unroll
    for (int nt = 0; nt < 2; ++nt) {
      const int oc = ochalf * 128 + wv * 32 + nt * 16 + cl;
#pragma unroll
      for (int ks = 0; ks < 6; ++ks)
        Bf[nt][ks].v8 = *reinterpret_cast<const bf16x8*>(cwb + oc * 192 + ks * 32 + g * 8);
    }
  }
  // pool biases hoisted
  float bias[2][3];
#pragma unroll
  for (int nt = 0; nt < 2; ++nt) {
    const int ocg = ochalf * 128 + wv * 32 + nt * 16 + cl;
    const int occ = (ocg < OCC) ? ocg : 0;
    bias[nt][0] = cb0[occ]; bias[nt][1] = cb1[occ]; bias[nt][2] = cb2[occ];
  }

  __syncthreads();  // widx + zeros ready

  // async W gather: rows 1..120, 6 x 16B granules each, XOR source-permute
  auto issue_gather = [&](int s, int nb) {
    const int* wr = &widx[s * 120];
#pragma unroll
    for (int i = 0; i < 4; ++i) {
      const int slotb = i * 256 + wv * 64;
      const int slot = slotb + lane;
      const int row = slot >> 3;
      const int c16 = (slot & 7) ^ (row & 7);
      bf16* dst = &xb[nb][slotb * 8];            // wave-uniform; HW adds lane*16B
      if (row >= 1 && row <= 120 && c16 < 6) {
        const int word = wr[row - 1] & 0xFFFF;
        const bf16* src = wsb + W2V48_OFF + word * 48 + c16 * 8;
        __builtin_amdgcn_global_load_lds(
            (const __attribute__((address_space(1))) void*)src,
            (__attribute__((address_space(3))) void*)dst, 16, 0, 0);
      }
    }
  };
  // reg-staged tail: chunks 6,7 (d48..59 + zeros), swizzled ds_write
  auto stage_tail = [&](int s, int nb) {
    if (t < 120) {
      const int wi = widx[s * 120 + t];
      const int word = wi & 0xFFFF;
      const int pidx = (wi >> 16) & 0xFFF;
      const int row = t + 1;
      const int wt = *(reinterpret_cast<const int*>(wsb + WTAIL_OFF) + word);
      const int4 pcA = *reinterpret_cast<const int4*>(wsb + PCAT_OFF + pidx * 16);
      const int4 pcB = *reinterpret_cast<const int4*>(wsb + PCAT_OFF + pidx * 16 + 8);
      const int sw6 = 6 ^ (row & 7), sw7 = 7 ^ (row & 7);
      *reinterpret_cast<int4*>(&xb[nb][row * XSTR + sw6 * 8]) = int4{wt, pcA.x, pcA.y, pcA.z};
      *reinterpret_cast<int4*>(&xb[nb][row * XSTR + sw7 * 8]) = pcB;
    }
  };

  issue_gather(0, 0);
  stage_tail(0, 0);
  asm volatile("s_waitcnt vmcnt(0)" ::: "memory");
  __syncthreads();

  int mrowT[8];
#pragma unroll
  for (int mt = 0; mt < 8; ++mt) {
    const int m = mt * 16 + cl;
    mrowT[mt] = (m < 120 ? m : 119) * XSTR;
  }

  for (int s = 0; s < 4; ++s) {
    const int nb = s & 1;
    if (s < 3) { issue_gather(s + 1, nb ^ 1); stage_tail(s + 1, nb ^ 1); }

    // conv GEMM: 96 MFMA/wave (8 mt x 2 nt x 6 ks), swizzled b128 A-reads
    f32x4 acc[8][2];
    const f32x4 z4 = {0.f, 0.f, 0.f, 0.f};
#pragma unroll
    for (int mt = 0; mt < 8; ++mt) { acc[mt][0] = z4; acc[mt][1] = z4; }

#pragma unroll
    for (int ks = 0; ks < 6; ++ks) {
      const int kp = ks * 32 + g * 8;
      const int tap = kp >> 6;
      const int d8 = (kp >> 3) & 7;
      const int sw = tap * XSTR + ((d8 ^ ((cl + tap) & 7)) << 3);
#pragma unroll
      for (int mt = 0; mt < 8; ++mt) {
        FragU a;
        a.v8 = *reinterpret_cast<const bf16x8*>(&xb[nb][mrowT[mt] + sw]);
#pragma unroll
        for (int nt = 0; nt < 2; ++nt)
          acc[mt][nt] = __builtin_amdgcn_mfma_f32_16x16x32_bf16(
              a.v8, Bf[nt][ks].v8, acc[mt][nt], 0, 0, 0);
      }
    }

    // piecewise masked max-pool (masked-out contributes 0)
    float pool[2][3];
#pragma unroll
    for (int nt = 0; nt < 2; ++nt) { pool[nt][0] = pool[nt][1] = pool[nt][2] = -INFINITY; }
#pragma unroll
    for (int mt = 0; mt < 8; ++mt) {
      const int l0 = mt * 16 + g * 4;
      if (l0 < 120) {
        const int4 pv = *reinterpret_cast<const int4*>(&widx[s * 120 + l0]);
        const int pcs[4] = {(int)((unsigned)pv.x >> 28), (int)((unsigned)pv.y >> 28),
                            (int)((unsigned)pv.z >> 28), (int)((unsigned)pv.w >> 28)};
#pragma unroll
        for (int r = 0; r < 4; ++r) {
          const int p = pcs[r];
#pragma unroll
          for (int nt = 0; nt < 2; ++nt) {
            const float v = acc[mt][nt][r];
            pool[nt][0] = fmaxf(pool[nt][0], p == 0 ? v : 0.0f);
            pool[nt][1] = fmaxf(pool[nt][1], p == 1 ? v : 0.0f);
            pool[nt][2] = fmaxf(pool[nt][2], p == 2 ? v : 0.0f);
          }
        }
      }
    }
#pragma unroll
    for (int nt = 0; nt < 2; ++nt)
#pragma unroll
      for (int p = 0; p < 3; ++p) {
        float x = pool[nt][p];
        x = fmaxf(x, __shfl_xor(x, 16));
        x = fmaxf(x, __shfl_xor(x, 32));
        pool[nt][p] = x;
      }
    if (g == 0) {
#pragma unroll
      for (int nt = 0; nt < 2; ++nt) {
        const int ocg = ochalf * 128 + wv * 32 + nt * 16 + cl;
        if (ocg < OCC) {
          bf16* fr = flws + (sb + s) * 768;
          fr[ocg]       = (bf16)tanhf(pool[nt][0] + bias[nt][0]);
          fr[256 + ocg] = (bf16)tanhf(pool[nt][1] + bias[nt][1]);
          fr[512 + ocg] = (bf16)tanhf(pool[nt][2] + bias[nt][2]);
        }
      }
    }

    asm volatile("s_waitcnt vmcnt(0)" ::: "memory");  // gather(s+1) landed
    __syncthreads();                                   // buffer handoff
  }
}

// ---- K2: batched logits GEMM + softmax + bag-max, one bag per block ----
__global__ __launch_bounds__(256)
void pcnn_logits(const bf16* __restrict__ wsb, const bf16* __restrict__ flws,
                 const float* __restrict__ rbias, float* __restrict__ out)
{
  __shared__ __align__(16) bf16 fl_lds[6144];  // [8 sent][768]
  __shared__ float logits_l[8][64];

  const int t = threadIdx.x;
  const int bag = blockIdx.x;
  const int wv = t >> 6, lane = t & 63, g = lane >> 4, cl = lane & 15;

#pragma unroll
  for (int j = 0; j < 3; ++j) {
    const bf16* src = flws + bag * 6144 + (j * 256 + t) * 8;
    bf16* dst = &fl_lds[(j * 256 + wv * 64) * 8];
    __builtin_amdgcn_global_load_lds(
        (const __attribute__((address_space(1))) void*)src,
        (__attribute__((address_space(3))) void*)dst, 16, 0, 0);
  }
  asm volatile("s_waitcnt vmcnt(0)" ::: "memory");
  __syncthreads();

  f32x4 lac = {0.f, 0.f, 0.f, 0.f};
  const bf16* brow = wsb + REMBB_OFF + (wv * 16 + cl) * 768 + g * 8;
  const bf16x8 zf = {(bf16)0.f, (bf16)0.f, (bf16)0.f, (bf16)0.f,
                     (bf16)0.f, (bf16)0.f, (bf16)0.f, (bf16)0.f};
#pragma unroll
  for (int ks = 0; ks < 24; ++ks) {
    const bf16x8 afr = (cl < 8)
        ? *reinterpret_cast<const bf16x8*>(&fl_lds[cl * 768 + ks * 32 + g * 8]) : zf;
    const bf16x8 bfr = *reinterpret_cast<const bf16x8*>(brow + ks * 32);
    lac = __builtin_amdgcn_mfma_f32_16x16x32_bf16(afr, bfr, lac, 0, 0, 0);
  }
  if (g < 2) {
    const int rel = wv * 16 + cl;
    const float bias = (rel < NRELS) ? rbias[rel] : 0.0f;
#pragma unroll
    for (int r = 0; r < 4; ++r)
      logits_l[g * 4 + r][rel] = lac[r] * 0.5f + bias;
  }
  __syncthreads();

#pragma unroll
  for (int rep = 0; rep < 2; ++rep) {
    const int s = wv + rep * 4;
    const float x = (lane < NRELS) ? logits_l[s][lane] : -INFINITY;
    float m = x;
#pragma unroll
    for (int off = 32; off; off >>= 1) m = fmaxf(m, __shfl_xor(m, off));
    const float e = (lane < NRELS) ? __expf(x - m) : 0.0f;
    float sm = e;
#pragma unroll
    for (int off = 32; off; off >>= 1) sm += __shfl_xor(sm, off);
    if (lane < NRELS) logits_l[s][lane] = x - m - __logf(sm);
  }
  __syncthreads();

  if (t < NRELS) {
    float m = logits_l[0][t];
#pragma unroll
    for (int s2 = 1; s2 < 8; ++s2) m = fmaxf(m, logits_l[s2][t]);
    out[bag * NRELS + t] = m;
  }
}

extern "C" void kernel_launch(void* const* d_in, const int* in_sizes, int n_in,
                              void* d_out, int out_size, void* d_ws, size_t ws_size,
                              hipStream_t stream) {
  const int* words  = (const int*)d_in[0];
  const int* posi   = (const int*)d_in[1];
  const float* w2v  = (const float*)d_in[2];
  const float* p1e  = (const float*)d_in[3];
  const float* p2e  = (const float*)d_in[4];
  const float* cw   = (const float*)d_in[5];
  const float* cb0  = (const float*)d_in[6];
  const float* cb1  = (const float*)d_in[7];
  const float* cb2  = (const float*)d_in[8];
  const float* remb = (const float*)d_in[9];
  const float* rbias= (const float*)d_in[10];
  bf16* wsb = (bf16*)d_ws;
  bf16* flws = wsb + FLWS_OFF;
  float* out = (float*)d_out;

  pcnn_prep<<<1445, 256, 0, stream>>>(w2v, p1e, p2e, remb, cw, wsb);
  pcnn_conv<<<4000, 256, 0, stream>>>(words, posi, cb0, cb1, cb2, wsb, flws);
  pcnn_logits<<<1000, 256, 0, stream>>>(wsb, flws, rbias, out);
}